// Round 10
// baseline (395.655 us; speedup 1.0000x reference)
//
#include <hip/hip_runtime.h>

typedef unsigned short u16;
typedef unsigned int   u32;

#define M_ROWS 10000
#define D_DIM  1433
#define KPAD   1472    // 23 * 64
#define NPAD   1536    // Wt rows (N dim of GEMM, 6 x 256)
#define MPAD   10240   // 40 * 256
#define N_EDGE 100000
#define HPAD   1440    // bf16 mx stride (720 u32)
#define HP32   720
#define NKT    23      // KPAD/64
#define EPS    1e-7f
#define BEPS   1e-5f
#define SC     0.6324555320336759f   // sqrt(0.4)

typedef __bf16 bf16x8 __attribute__((ext_vector_type(8)));
typedef float  f32x4  __attribute__((ext_vector_type(4)));
typedef u32    u32x4  __attribute__((ext_vector_type(4)));

__device__ __forceinline__ u16 f2bf(float f) {
  union { float f; unsigned u; } v; v.f = f;
  unsigned r = v.u + 0x7FFFu + ((v.u >> 16) & 1u);
  return (u16)(r >> 16);
}
__device__ __forceinline__ u32 pack2bf(float lo, float hi) {
  return (u32)f2bf(lo) | ((u32)f2bf(hi) << 16);
}
__device__ __forceinline__ float bflo(u32 u) { return __uint_as_float(u << 16); }
__device__ __forceinline__ float bfhi(u32 u) { return __uint_as_float(u & 0xFFFF0000u); }

__device__ __forceinline__ float atanh_f(float y) {
  return 0.5f * logf((1.f + y) / (1.f - y));
}

__device__ __forceinline__ void gl_lds16(const u16* g, u16* l) {
  __builtin_amdgcn_global_load_lds((const __attribute__((address_space(1))) void*)(const void*)g,
                                   (__attribute__((address_space(3))) void*)(void*)l,
                                   16, 0, 0);
}

#define BAR() asm volatile("s_barrier" ::: "memory")

// ---------------- GEMM 256x256, 4 waves, 128x128 output per wave -------------
// R14: LDS-traffic reduction (register blocking). Serial-sum model (7 schedule
// variants all confirm): tile time = LDS demand + MFMA demand + drain =
// 192 b128 x 12 + 512 MFMA x 4.85 + drain ~= 5740 cyc. Schedule reorders were
// all null; this cuts the LDS term: 4 waves x (8 A + 8 B frags) x 2 ks =
// 128 b128/tile (-33%), same MFMA work, same per-element accumulate order
// (bit-identical C). acc[8][8] = 256 VGPR -> 1 wave/SIMD (bounds (256,1)).
// Stage: 16 loads/tile (256 thr); ledger: prologue 16, vmcnt(4); phaseA +12,
// vmcnt(12) retires A2(kt); phaseB +4, vmcnt(4) retires B+A1(kt+1); tail 0.
// Frag reads: same 16-row pattern + XOR as R9 -> provably 0 bank conflicts.
// C[i,j] = sum_k A[i,k]*B[j,k]; writes 0 to pad cols [D_DIM,HPAD).
__global__ __launch_bounds__(256, 1) void gemm256(
    const u16* __restrict__ A,
    const u16* __restrict__ B,
    u16* __restrict__ C,
    float* __restrict__ nrm)
{
  __shared__ u16 lds[2][2][256 * 64];   // 128 KiB

  const int tid  = threadIdx.x;
  const int lane = tid & 63;
  const int w    = tid >> 6;       // 4 waves
  const int wr   = w >> 1;         // M half (0: rows 0-127, 1: 128-255)
  const int wc   = w & 1;          // N half

  // XCD-chunked bijective swizzle: 240 = 8 * 30, y-fastest within chunk
  const int flat = blockIdx.x;
  const int wgid = (flat & 7) * 30 + (flat >> 3);
  const int gy = wgid % 6;
  const int gx = wgid / 6;
  const long arow0 = (long)gx * 256;
  const long brow0 = (long)gy * 256;

  f32x4 acc[8][8] = {};            // 256 VGPR accumulator

  const int sr8 = lane >> 3;
  const int scb = ((lane & 7) << 4) ^ (sr8 << 4);
  const int l15 = lane & 15;
  const int khi = (lane >> 4) << 4;

  // stage call l covers rows l*32 + w*8 + sr8 (32 rows/call; HW adds lane*16B)
  auto STG_B = [&](int b, int kt) {
    const long k0 = (long)kt * 64 + (scb >> 1);
#pragma unroll
    for (int l = 0; l < 8; ++l) {
      const int r   = l * 32 + w * 8 + sr8;
      const int dst = l * 2048 + w * 512;
      gl_lds16(B + (brow0 + r) * KPAD + k0, &lds[b][1][dst]);
    }
  };
  // sel=0: l {0,1,4,5} = rows 0-63,128-191 (phase-A rows for both wr);
  // sel=1: l {2,3,6,7} = rows 64-127,192-255 (phase-B rows).
  auto STG_A = [&](int b, int kt, int sel) {
    const long k0 = (long)kt * 64 + (scb >> 1);
#pragma unroll
    for (int g = 0; g < 4; ++g) {
      const int l   = (g >> 1) * 4 + sel * 2 + (g & 1);
      const int r   = l * 32 + w * 8 + sr8;
      const int dst = l * 2048 + w * 512;
      gl_lds16(A + (arow0 + r) * KPAD + k0, &lds[b][0][dst]);
    }
  };

  // prologue: full tile 0 (B:8, A1:4, A2:4); retire B+A1 (oldest 12)
  STG_B(0, 0); STG_A(0, 0, 0); STG_A(0, 0, 1);
  asm volatile("s_waitcnt vmcnt(4)" ::: "memory");
  BAR();

  for (int kt = 0; kt < NKT; ++kt) {
    const int b = kt & 1;
    const bool pf = (kt + 1 < NKT);

    // ============ phase A: mi 0..3 (rows wr*128+0..63) ============
    bf16x8 b0[8], b1[8], a0[4], a1[4];
#pragma unroll
    for (int ni = 0; ni < 8; ++ni) {
      const int row = wc * 128 + ni * 16 + l15;
      const int kb0 = (khi) ^ ((row & 7) << 4);
      const int kb1 = (64 + khi) ^ ((row & 7) << 4);
      b0[ni] = *(const bf16x8*)&lds[b][1][row * 64 + (kb0 >> 1)];
      b1[ni] = *(const bf16x8*)&lds[b][1][row * 64 + (kb1 >> 1)];
    }
#pragma unroll
    for (int mi = 0; mi < 4; ++mi) {
      const int row = wr * 128 + mi * 16 + l15;
      const int kb0 = (khi) ^ ((row & 7) << 4);
      const int kb1 = (64 + khi) ^ ((row & 7) << 4);
      a0[mi] = *(const bf16x8*)&lds[b][0][row * 64 + (kb0 >> 1)];
      a1[mi] = *(const bf16x8*)&lds[b][0][row * 64 + (kb1 >> 1)];
    }
    if (pf) { STG_B(b ^ 1, kt + 1); STG_A(b ^ 1, kt + 1, 0); }   // 12 loads
    __builtin_amdgcn_s_setprio(1);
#pragma unroll
    for (int mi = 0; mi < 4; ++mi)
#pragma unroll
      for (int ni = 0; ni < 8; ++ni)
        acc[mi][ni] = __builtin_amdgcn_mfma_f32_16x16x32_bf16(a0[mi], b0[ni], acc[mi][ni], 0, 0, 0);
#pragma unroll
    for (int mi = 0; mi < 4; ++mi)
#pragma unroll
      for (int ni = 0; ni < 8; ++ni)
        acc[mi][ni] = __builtin_amdgcn_mfma_f32_16x16x32_bf16(a1[mi], b1[ni], acc[mi][ni], 0, 0, 0);
    __builtin_amdgcn_s_setprio(0);
    if (pf) asm volatile("s_waitcnt vmcnt(12)" ::: "memory");  // A2(kt) landed
    else    asm volatile("s_waitcnt vmcnt(0)" ::: "memory");
    BAR();

    // ============ phase B: mi 4..7 (rows wr*128+64..127) ============
    bf16x8 c0[4], c1[4];
#pragma unroll
    for (int mi = 0; mi < 4; ++mi) {
      const int row = wr * 128 + (4 + mi) * 16 + l15;
      const int kb0 = (khi) ^ ((row & 7) << 4);
      const int kb1 = (64 + khi) ^ ((row & 7) << 4);
      c0[mi] = *(const bf16x8*)&lds[b][0][row * 64 + (kb0 >> 1)];
      c1[mi] = *(const bf16x8*)&lds[b][0][row * 64 + (kb1 >> 1)];
    }
    if (pf) STG_A(b ^ 1, kt + 1, 1);                            // 4 loads
    __builtin_amdgcn_s_setprio(1);
#pragma unroll
    for (int mi = 0; mi < 4; ++mi)
#pragma unroll
      for (int ni = 0; ni < 8; ++ni)
        acc[4 + mi][ni] = __builtin_amdgcn_mfma_f32_16x16x32_bf16(c0[mi], b0[ni], acc[4 + mi][ni], 0, 0, 0);
#pragma unroll
    for (int mi = 0; mi < 4; ++mi)
#pragma unroll
      for (int ni = 0; ni < 8; ++ni)
        acc[4 + mi][ni] = __builtin_amdgcn_mfma_f32_16x16x32_bf16(c1[mi], b1[ni], acc[4 + mi][ni], 0, 0, 0);
    __builtin_amdgcn_s_setprio(0);
    if (pf) asm volatile("s_waitcnt vmcnt(4)" ::: "memory");    // B+A1(kt+1) landed
    BAR();
  }

  const int orw = (lane >> 4) * 4;   // C/D: row = (lane>>4)*4 + reg, col = lane&15
  const int ocl = lane & 15;

  // per-row sum(mx^2) partials -> one atomic per row per (block, wc)
#pragma unroll
  for (int mi = 0; mi < 8; ++mi)
#pragma unroll
    for (int r = 0; r < 4; ++r) {
      float s = 0.f;
#pragma unroll
      for (int ni = 0; ni < 8; ++ni) {
        const long j = brow0 + wc * 128 + ni * 16 + ocl;
        const float v = acc[mi][ni][r];
        s += (j < D_DIM) ? v * v : 0.f;
      }
      s += __shfl_xor(s, 1, 64);
      s += __shfl_xor(s, 2, 64);
      s += __shfl_xor(s, 4, 64);
      s += __shfl_xor(s, 8, 64);
      if ((lane & 15) == 0)
        atomicAdd(&nrm[arow0 + wr * 128 + mi * 16 + orw + r], s);
    }

#pragma unroll
  for (int mi = 0; mi < 8; ++mi) {
    const long i0 = arow0 + wr * 128 + mi * 16 + orw;
    if (i0 >= M_ROWS) continue;
#pragma unroll
    for (int ni = 0; ni < 8; ++ni) {
      const long j = brow0 + wc * 128 + ni * 16 + ocl;
      if (j >= HPAD) continue;
#pragma unroll
      for (int r = 0; r < 4; ++r) {
        const long i = i0 + r;
        if (i < M_ROWS) C[i * HPAD + j] = (j < D_DIM) ? f2bf(acc[mi][ni][r]) : (u16)0;
      }
    }
  }
}

// ---------------- rowwise helpers ------------------------------------------
template<int NW>
__device__ __forceinline__ float2 block_reduce2(float a, float b) {
  __shared__ float sa[NW], sb[NW];
#pragma unroll
  for (int off = 32; off > 0; off >>= 1) {
    a += __shfl_down(a, off, 64);
    b += __shfl_down(b, off, 64);
  }
  const int tid = threadIdx.x;
  if ((tid & 63) == 0) { sa[tid >> 6] = a; sb[tid >> 6] = b; }
  __syncthreads();
  float ra = 0.f, rb = 0.f;
#pragma unroll
  for (int i = 0; i < NW; ++i) { ra += sa[i]; rb += sb[i]; }
  __syncthreads();
  return make_float2(ra, rb);
}

// pre: t = logmap0(expmap0(x,c), c), bf16 (K zero-padded), xn = ||t||
__global__ __launch_bounds__(256) void pre_k(const float* __restrict__ x,
                                             u16* __restrict__ t,
                                             float* __restrict__ xn) {
  const long i = blockIdx.x;
  const int tid = threadIdx.x;
  u16* trow = t + i * KPAD;
  if (i >= M_ROWS) {
#pragma unroll
    for (int jj = 0; jj < 6; ++jj) { int j = tid + jj * 256; if (j < KPAD) trow[j] = 0; }
    return;
  }
  const float* xr = x + i * D_DIM;
  float v[6]; float s2 = 0.f;
#pragma unroll
  for (int jj = 0; jj < 6; ++jj) {
    int j = tid + jj * 256;
    v[jj] = (j < D_DIM) ? xr[j] : 0.f;
    s2 += v[jj] * v[jj];
  }
  s2 = block_reduce2<4>(s2, 0.f).x;
  const float nx_t = sqrtf(s2);
  const float nx   = fmaxf(nx_t, EPS);
  const float al   = tanhf(SC * nx) / (SC * nx);
  const float n1   = fmaxf(al * nx_t, EPS);
  const float be   = atanh_f(fminf(SC * n1, 1.f - BEPS)) / (SC * n1);
  const float sca  = al * be;
  if (tid == 0) xn[i] = fmaxf(sca * nx_t, EPS);
#pragma unroll
  for (int jj = 0; jj < 6; ++jj) {
    int j = tid + jj * 256;
    if (j < KPAD) trow[j] = (j < D_DIM) ? f2bf(sca * v[jj]) : (u16)0;
  }
}

__global__ void zero_f(float* p, int n) {
  int i = blockIdx.x * 256 + threadIdx.x;
  if (i < n) p[i] = 0.f;
}

// fold (with inline per-edge Mobius/proj scale):
// pe[e] = (col u16 << 16) | bf16(w_e * S[col]),
//   S[c] from nrm[c] (sum mx^2) and xn[c] (||t||).
__global__ void fold_k(const int* __restrict__ ecol, const float* __restrict__ eval,
                       const float* __restrict__ nrm, const float* __restrict__ xn,
                       u32* __restrict__ pe, int E) {
  const int e = blockIdx.x * 256 + threadIdx.x;
  if (e >= E) return;
  const int c = ecol[e];
  const float realn = sqrtf(nrm[c]);
  const float mxn   = fmaxf(realn, EPS);
  const float xi    = xn[c];
  const float tf    = tanhf((mxn / xi) * atanh_f(fminf(xi, 1.f - BEPS)));
  float S = tf / mxn;
  const float hn = fmaxf(S * realn, EPS);
  const float maxn = 1.f - BEPS;
  if (hn > maxn) S *= maxn / hn;
  pe[e] = ((u32)c << 16) | (u32)f2bf(eval[e] * S);
}

// fused spmm + post (session best form): 256-thread blocks, clamped 12-deep
// edge loop (fully pipelined, no serial remainder). One row per block.
// last==0: writes t_next bf16 (KPAD, zero pad) + xn.  last==1: writes out f32.
__global__ __launch_bounds__(256) void spmm_post(const int* __restrict__ rp,
                                                 const u32* __restrict__ pe,
                                                 const u32* __restrict__ mxp,
                                                 u16* __restrict__ t,
                                                 float* __restrict__ xn,
                                                 float* __restrict__ out,
                                                 const int last) {
  const long r = blockIdx.x;
  const int tid = threadIdx.x;
  if (r >= M_ROWS) {
    if (!last && tid < 184) {            // 184 * 4 u32 = 736 = KPAD/2 words
      u32* trow32 = (u32*)(t + r * KPAD);
#pragma unroll
      for (int k = 0; k < 4; ++k) trow32[4 * tid + k] = 0u;
    }
    return;
  }
  const bool act = tid < 180;           // 180 * 4 u32 = 720 words
  const long boff = 4 * tid;
  float a[8] = {0.f, 0.f, 0.f, 0.f, 0.f, 0.f, 0.f, 0.f};
  const int e0 = rp[r], e1 = rp[r + 1];
  for (int e = e0; e < e1; e += 12) {
    u32 pp[12]; float w[12];
#pragma unroll
    for (int j = 0; j < 12; ++j) {
      const int ee = e + j;
      const int ec = (ee < e1) ? ee : (e1 - 1);
      pp[j] = pe[ec];
      w[j]  = (ee < e1) ? bflo(pp[j]) : 0.f;
    }
    if (act) {
      u32x4 q[12];
#pragma unroll
      for (int j = 0; j < 12; ++j)
        q[j] = *(const u32x4*)&mxp[(long)(pp[j] >> 16) * HP32 + boff];
#pragma unroll
      for (int j = 0; j < 12; ++j) {
#pragma unroll
        for (int k = 0; k < 4; ++k) {
          a[2 * k]     += w[j] * bflo(q[j][k]);
          a[2 * k + 1] += w[j] * bfhi(q[j][k]);
        }
      }
    }
  }
  float s2 = 0.f, s2p = 0.f;
#pragma unroll
  for (int k = 0; k < 8; ++k) {
    const int col = 8 * tid + k;
    const float v = (act && col < D_DIM) ? a[k] : 0.f;
    a[k] = v;
    s2 += v * v;
    const float p = fmaxf(v, 0.f);
    s2p += p * p;
  }
  const float2 red = block_reduce2<4>(s2, s2p);
  const float ns_t  = sqrtf(red.x);
  const float nsp_t = sqrtf(red.y);
  const float maxn = (1.f - BEPS) / SC;
  const float ns = fmaxf(ns_t, EPS);
  const float al = tanhf(SC * ns) / (SC * ns);
  const float n1 = fmaxf(al * ns_t, EPS);
  const float be = (n1 > maxn) ? (maxn / n1) : 1.f;
  const float n2 = fmaxf(be * al * ns_t, EPS);
  const float lam = atanh_f(fminf(SC * n2, 1.f - BEPS)) / (SC * n2);
  const float g = lam * be * al;
  const float na_t = g * nsp_t;
  const float n3 = fmaxf(na_t, EPS);
  const float mu = tanhf(SC * n3) / (SC * n3);
  const float n4 = fmaxf(mu * na_t, EPS);
  const float nu = (n4 > maxn) ? (maxn / n4) : 1.f;
  const float T = nu * mu * g;            // h_out = T * relu(s)
  if (last) {
    if (act) {
      float* orow = out + r * (long)D_DIM;
#pragma unroll
      for (int k = 0; k < 8; ++k) {
        const int col = 8 * tid + k;
        if (col < D_DIM) orow[col] = T * fmaxf(a[k], 0.f);
      }
    }
  } else {
    const float nh_t = T * nsp_t;
    const float n5 = fmaxf(nh_t, EPS);
    const float kap = atanh_f(fminf(SC * n5, 1.f - BEPS)) / (SC * n5);
    const float F = kap * T;              // t_next = F * relu(s)
    if (tid == 0) xn[r] = fmaxf(F * nsp_t, EPS);
    u32* trow32 = (u32*)(t + r * KPAD);
    if (act) {
#pragma unroll
      for (int k = 0; k < 4; ++k)
        trow32[4 * tid + k] = pack2bf(F * fmaxf(a[2 * k], 0.f), F * fmaxf(a[2 * k + 1], 0.f));
    } else if (tid < 184) {
#pragma unroll
      for (int k = 0; k < 4; ++k) trow32[4 * tid + k] = 0u;   // cols [1440,1472)
    }
  }
}

// ---------------- W transpose+cast: Wt[n][k] = bf16(W[k][n]), zero padded ----
// Wt is NPAD rows (n) x KPAD cols (k).
__global__ void wt_conv(const float* __restrict__ W, u16* __restrict__ Wt) {
  __shared__ float tile[32][33];
  const int kb = blockIdx.x * 32, nb = blockIdx.y * 32;
  const int tx = threadIdx.x, ty = threadIdx.y;  // 32x8
#pragma unroll
  for (int r = 0; r < 32; r += 8) {
    const int k = kb + ty + r, n = nb + tx;
    tile[ty + r][tx] = (k < D_DIM && n < D_DIM) ? W[(long)k * D_DIM + n] : 0.f;
  }
  __syncthreads();
#pragma unroll
  for (int r = 0; r < 32; r += 8) {
    const int n = nb + ty + r, k = kb + tx;
    if (n < NPAD && k < KPAD) Wt[(long)n * KPAD + k] = f2bf(tile[tx][ty + r]);
  }
}

// ---------------- CSR build -------------------------------------------------
__global__ void zero_int(int* p, int n) {
  int i = blockIdx.x * 256 + threadIdx.x;
  if (i < n) p[i] = 0;
}
__global__ void hist_k(const int* __restrict__ rows, int* __restrict__ counts, int E) {
  int e = blockIdx.x * 256 + threadIdx.x;
  if (e < E) atomicAdd(&counts[rows[e]], 1);
}
// wave-shuffle scan -- 4 barriers/1024-chunk. Exact integer prefix sum.
__global__ __launch_bounds__(1024) void scan_rp(const int* __restrict__ counts,
                                                int* __restrict__ rp, int n) {
  __shared__ int swv[16];
  __shared__ int carry_s;
  const int tid  = threadIdx.x;
  const int lane = tid & 63;
  const int wid  = tid >> 6;
  if (tid == 0) { carry_s = 0; rp[0] = 0; }
  __syncthreads();
  for (int base = 0; base < n; base += 1024) {
    const int i = base + tid;
    int v = (i < n) ? counts[i] : 0;
#pragma unroll
    for (int off = 1; off < 64; off <<= 1) {
      const int tv = __shfl_up(v, off, 64);
      if (lane >= off) v += tv;
    }
    if (lane == 63) swv[wid] = v;
    __syncthreads();
    if (wid == 0) {
      int s = (lane < 16) ? swv[lane] : 0;
#pragma unroll
      for (int off = 1; off < 16; off <<= 1) {
        const int tv = __shfl_up(s, off, 64);
        if (lane >= off) s += tv;
      }
      if (lane < 16) swv[lane] = s;      // inclusive wave totals
    }
    __syncthreads();
    const int wpfx  = (wid > 0) ? swv[wid - 1] : 0;
    const int carry = carry_s;
    if (i < n) rp[i + 1] = carry + wpfx + v;
    __syncthreads();
    if (tid == 1023) carry_s = carry + swv[15];
    __syncthreads();
  }
}
__global__ void scatter_k(const int* __restrict__ rows, const int* __restrict__ cols,
                          const float* __restrict__ vals, const int* __restrict__ rp,
                          int* __restrict__ cursor, int* __restrict__ ecol,
                          float* __restrict__ eval, int E) {
  int e = blockIdx.x * 256 + threadIdx.x;
  if (e < E) {
    const int r = rows[e];
    const int pos = rp[r] + atomicAdd(&cursor[r], 1);
    ecol[pos] = cols[e];
    eval[pos] = vals[e];
  }
}

// ---------------- launch -----------------------------------------------------
extern "C" void kernel_launch(void* const* d_in, const int* in_sizes, int n_in,
                              void* d_out, int out_size, void* d_ws, size_t ws_size,
                              hipStream_t stream) {
  (void)in_sizes; (void)n_in; (void)out_size; (void)ws_size;
  const float* x    = (const float*)d_in[0];
  const float* W[3] = {(const float*)d_in[1], (const float*)d_in[2], (const float*)d_in[3]};
  const float* vals = (const float*)d_in[4];
  const int*   rows = (const int*)d_in[5];
  const int*   cols = (const int*)d_in[6];
  float* out = (float*)d_out;

  char* base = (char*)d_ws;
  size_t off = 0;
  auto take = [&](size_t bytes) {
    void* q = base + off;
    off = (off + bytes + 255) & ~(size_t)255;
    return q;
  };
  u16*   t    = (u16*)take((size_t)MPAD * KPAD * 2);
  u16*   Wt   = (u16*)take((size_t)NPAD * KPAD * 2);
  u16*   mx   = (u16*)take((size_t)M_ROWS * HPAD * 2);   // bf16 GEMM out
  float* nrm3 = (float*)take((size_t)3 * MPAD * 4);      // per-layer, zeroed once
  float* xn   = (float*)take((size_t)M_ROWS * 4);
  int*   cnt  = (int*)take((size_t)M_ROWS * 2 * 4);      // counts | cursor
  int*   rp   = (int*)take((size_t)(M_ROWS + 1) * 4);
  int*   ecol = (int*)take((size_t)N_EDGE * 4);
  float* eval = (float*)take((size_t)N_EDGE * 4);
  u32*   pe   = (u32*)take((size_t)N_EDGE * 4);

  // CSR build (rows/cols/vals identical across layers)
  zero_int<<<(2 * M_ROWS + 255) / 256, 256, 0, stream>>>(cnt, 2 * M_ROWS);
  hist_k<<<(N_EDGE + 255) / 256, 256, 0, stream>>>(rows, cnt, N_EDGE);
  scan_rp<<<1, 1024, 0, stream>>>(cnt, rp, M_ROWS);
  scatter_k<<<(N_EDGE + 255) / 256, 256, 0, stream>>>(rows, cols, vals, rp,
                                                      cnt + M_ROWS, ecol, eval, N_EDGE);
  zero_f<<<(3 * MPAD + 255) / 256, 256, 0, stream>>>(nrm3, 3 * MPAD);

  pre_k<<<MPAD, 256, 0, stream>>>(x, t, xn);

  for (int L = 0; L < 3; ++L) {
    float* nrm = nrm3 + (size_t)L * MPAD;
    wt_conv<<<dim3(46, 48), dim3(32, 8), 0, stream>>>(W[L], Wt);
    gemm256<<<240, 256, 0, stream>>>(t, Wt, mx, nrm);
    fold_k<<<(N_EDGE + 255) / 256, 256, 0, stream>>>(ecol, eval, nrm, xn, pe, N_EDGE);
    spmm_post<<<MPAD, 256, 0, stream>>>(rp, pe, (const u32*)mx, t, xn, out, (L == 2) ? 1 : 0);
  }
}

// Round 11
// 360.553 us; speedup vs baseline: 1.0974x; 1.0974x over previous
//
#include <hip/hip_runtime.h>

typedef unsigned short u16;
typedef unsigned int   u32;

#define M_ROWS 10000
#define D_DIM  1433
#define KPAD   1472    // 23 * 64
#define NPAD   1536    // Wt rows (N dim of GEMM, 6 x 256)
#define MPAD   10240   // 40 * 256
#define N_EDGE 100000
#define HPAD   1440    // bf16 mx stride (720 u32)
#define HP32   720
#define NKT    23      // KPAD/64
#define EPS    1e-7f
#define BEPS   1e-5f
#define SC     0.6324555320336759f   // sqrt(0.4)

typedef __bf16 bf16x8 __attribute__((ext_vector_type(8)));
typedef float  f32x4  __attribute__((ext_vector_type(4)));
typedef u32    u32x4  __attribute__((ext_vector_type(4)));

__device__ __forceinline__ u16 f2bf(float f) {
  union { float f; unsigned u; } v; v.f = f;
  unsigned r = v.u + 0x7FFFu + ((v.u >> 16) & 1u);
  return (u16)(r >> 16);
}
__device__ __forceinline__ u32 pack2bf(float lo, float hi) {
  return (u32)f2bf(lo) | ((u32)f2bf(hi) << 16);
}
__device__ __forceinline__ float bflo(u32 u) { return __uint_as_float(u << 16); }
__device__ __forceinline__ float bfhi(u32 u) { return __uint_as_float(u & 0xFFFF0000u); }

__device__ __forceinline__ float atanh_f(float y) {
  return 0.5f * logf((1.f + y) / (1.f - y));
}

__device__ __forceinline__ void gl_lds16(const u16* g, u16* l) {
  __builtin_amdgcn_global_load_lds((const __attribute__((address_space(1))) void*)(const void*)g,
                                   (__attribute__((address_space(3))) void*)(void*)l,
                                   16, 0, 0);
}

#define BAR() asm volatile("s_barrier" ::: "memory")

// ---------------- GEMM 256x256, 8 waves (R13 -- session best, CLOSED) --------
// 2-phase split + counted vmcnt (6/2), 2 barriers/tile, setprio around MFMA,
// NKT=23 (K=1472 covers D=1433). NINE variants bracket this structure:
// {1-bar: 75.4, 8-phase: 84, 128^2x3blk: ~59ig, 2ph: 72.6, 4ph-m201: 76,
//  SGB: 73.4, 32x32-shape: 97 (4-way LDS conflict), 4-wave-regblock: 119
//  (TLP collapse at 1 wave/SIMD)}. ~840 TF in-graph = plain-HIP ceiling for
// this shape (matches documented m97-structure ceiling). DO NOT TOUCH.
// C[i,j] = sum_k A[i,k]*B[j,k]; writes 0 to pad cols [D_DIM,HPAD).
__global__ __launch_bounds__(512, 1) void gemm256(
    const u16* __restrict__ A,
    const u16* __restrict__ B,
    u16* __restrict__ C,
    float* __restrict__ nrm)
{
  __shared__ u16 lds[2][2][256 * 64];   // 128 KiB

  const int tid  = threadIdx.x;
  const int lane = tid & 63;
  const int w    = tid >> 6;
  const int wr   = w >> 2;
  const int wc   = w & 3;

  // XCD-chunked bijective swizzle: 240 = 8 * 30, y-fastest within chunk
  const int flat = blockIdx.x;
  const int wgid = (flat & 7) * 30 + (flat >> 3);
  const int gy = wgid % 6;
  const int gx = wgid / 6;
  const long arow0 = (long)gx * 256;
  const long brow0 = (long)gy * 256;

  f32x4 acc[8][4] = {};

  const int sr8 = lane >> 3;
  const int scb = ((lane & 7) << 4) ^ (sr8 << 4);
  const int l15 = lane & 15;
  const int khi = (lane >> 4) << 4;

  auto STG_B = [&](int b, int kt) {
    const long k0 = (long)kt * 64 + (scb >> 1);
#pragma unroll
    for (int l = 0; l < 4; ++l) {
      const int r   = l * 64 + w * 8 + sr8;
      const int dst = l * 4096 + w * 512;
      gl_lds16(B + (brow0 + r) * KPAD + k0, &lds[b][1][dst]);
    }
  };
  auto STG_A = [&](int b, int kt, int sel) {
    const long k0 = (long)kt * 64 + (scb >> 1);
#pragma unroll
    for (int li = 0; li < 2; ++li) {
      const int l   = sel + 2 * li;
      const int r   = l * 64 + w * 8 + sr8;
      const int dst = l * 4096 + w * 512;
      gl_lds16(A + (arow0 + r) * KPAD + k0, &lds[b][0][dst]);
    }
  };

  // prologue: full tile 0, drain, barrier
  STG_B(0, 0); STG_A(0, 0, 0); STG_A(0, 0, 1);
  asm volatile("s_waitcnt vmcnt(0)" ::: "memory");
  BAR();

  for (int kt = 0; kt < NKT; ++kt) {
    const int b = kt & 1;
    const bool pf = (kt + 1 < NKT);

    // ================= phase A (mh = 0) =================
    bf16x8 b0[4], b1[4], a0[4], a1[4];
#pragma unroll
    for (int ni = 0; ni < 4; ++ni) {
      const int row = wc * 64 + ni * 16 + l15;
      const int kb0 = (khi) ^ ((row & 7) << 4);
      const int kb1 = (64 + khi) ^ ((row & 7) << 4);
      b0[ni] = *(const bf16x8*)&lds[b][1][row * 64 + (kb0 >> 1)];
      b1[ni] = *(const bf16x8*)&lds[b][1][row * 64 + (kb1 >> 1)];
    }
#pragma unroll
    for (int ml = 0; ml < 4; ++ml) {
      const int row = wr * 128 + ml * 16 + l15;
      const int kb0 = (khi) ^ ((row & 7) << 4);
      const int kb1 = (64 + khi) ^ ((row & 7) << 4);
      a0[ml] = *(const bf16x8*)&lds[b][0][row * 64 + (kb0 >> 1)];
      a1[ml] = *(const bf16x8*)&lds[b][0][row * 64 + (kb1 >> 1)];
    }
    if (pf) { STG_B(b ^ 1, kt + 1); STG_A(b ^ 1, kt + 1, 0); }   // 6 loads
    __builtin_amdgcn_s_setprio(1);
#pragma unroll
    for (int ml = 0; ml < 4; ++ml)
#pragma unroll
      for (int ni = 0; ni < 4; ++ni)
        acc[ml][ni] = __builtin_amdgcn_mfma_f32_16x16x32_bf16(a0[ml], b0[ni], acc[ml][ni], 0, 0, 0);
#pragma unroll
    for (int ml = 0; ml < 4; ++ml)
#pragma unroll
      for (int ni = 0; ni < 4; ++ni)
        acc[ml][ni] = __builtin_amdgcn_mfma_f32_16x16x32_bf16(a1[ml], b1[ni], acc[ml][ni], 0, 0, 0);
    __builtin_amdgcn_s_setprio(0);
    if (pf) asm volatile("s_waitcnt vmcnt(6)" ::: "memory");   // A13(kt) landed
    else    asm volatile("s_waitcnt vmcnt(0)" ::: "memory");
    BAR();

    // ================= phase B (mh = 1) =================
    bf16x8 c0[4], c1[4];
#pragma unroll
    for (int ml = 0; ml < 4; ++ml) {
      const int row = wr * 128 + (4 + ml) * 16 + l15;
      const int kb0 = (khi) ^ ((row & 7) << 4);
      const int kb1 = (64 + khi) ^ ((row & 7) << 4);
      c0[ml] = *(const bf16x8*)&lds[b][0][row * 64 + (kb0 >> 1)];
      c1[ml] = *(const bf16x8*)&lds[b][0][row * 64 + (kb1 >> 1)];
    }
    if (pf) STG_A(b ^ 1, kt + 1, 1);                            // 2 loads
    __builtin_amdgcn_s_setprio(1);
#pragma unroll
    for (int ml = 0; ml < 4; ++ml)
#pragma unroll
      for (int ni = 0; ni < 4; ++ni)
        acc[4 + ml][ni] = __builtin_amdgcn_mfma_f32_16x16x32_bf16(c0[ml], b0[ni], acc[4 + ml][ni], 0, 0, 0);
#pragma unroll
    for (int ml = 0; ml < 4; ++ml)
#pragma unroll
      for (int ni = 0; ni < 4; ++ni)
        acc[4 + ml][ni] = __builtin_amdgcn_mfma_f32_16x16x32_bf16(c1[ml], b1[ni], acc[4 + ml][ni], 0, 0, 0);
    __builtin_amdgcn_s_setprio(0);
    if (pf) asm volatile("s_waitcnt vmcnt(2)" ::: "memory");    // B+A02(kt+1) landed
    BAR();
  }

  const int orw = (lane >> 4) * 4;   // C/D: row = (lane>>4)*4 + reg, col = lane&15
  const int ocl = lane & 15;

  // per-row sum(mx^2) partials -> one atomic per row per block
#pragma unroll
  for (int mi = 0; mi < 8; ++mi)
#pragma unroll
    for (int r = 0; r < 4; ++r) {
      float s = 0.f;
#pragma unroll
      for (int ni = 0; ni < 4; ++ni) {
        const long j = brow0 + wc * 64 + ni * 16 + ocl;
        const float v = acc[mi][ni][r];
        s += (j < D_DIM) ? v * v : 0.f;
      }
      s += __shfl_xor(s, 1, 64);
      s += __shfl_xor(s, 2, 64);
      s += __shfl_xor(s, 4, 64);
      s += __shfl_xor(s, 8, 64);
      if ((lane & 15) == 0)
        atomicAdd(&nrm[arow0 + wr * 128 + mi * 16 + orw + r], s);
    }

#pragma unroll
  for (int mi = 0; mi < 8; ++mi) {
    const long i0 = arow0 + wr * 128 + mi * 16 + orw;
    if (i0 >= M_ROWS) continue;
#pragma unroll
    for (int ni = 0; ni < 4; ++ni) {
      const long j = brow0 + wc * 64 + ni * 16 + ocl;
      if (j >= HPAD) continue;
#pragma unroll
      for (int r = 0; r < 4; ++r) {
        const long i = i0 + r;
        if (i < M_ROWS) C[i * HPAD + j] = (j < D_DIM) ? f2bf(acc[mi][ni][r]) : (u16)0;
      }
    }
  }
}

// ---------------- rowwise helpers ------------------------------------------
template<int NW>
__device__ __forceinline__ float2 block_reduce2(float a, float b) {
  __shared__ float sa[NW], sb[NW];
#pragma unroll
  for (int off = 32; off > 0; off >>= 1) {
    a += __shfl_down(a, off, 64);
    b += __shfl_down(b, off, 64);
  }
  const int tid = threadIdx.x;
  if ((tid & 63) == 0) { sa[tid >> 6] = a; sb[tid >> 6] = b; }
  __syncthreads();
  float ra = 0.f, rb = 0.f;
#pragma unroll
  for (int i = 0; i < NW; ++i) { ra += sa[i]; rb += sb[i]; }
  __syncthreads();
  return make_float2(ra, rb);
}

// pre: t = logmap0(expmap0(x,c), c), bf16 (K zero-padded), xn = ||t||
__global__ __launch_bounds__(256) void pre_k(const float* __restrict__ x,
                                             u16* __restrict__ t,
                                             float* __restrict__ xn) {
  const long i = blockIdx.x;
  const int tid = threadIdx.x;
  u16* trow = t + i * KPAD;
  if (i >= M_ROWS) {
#pragma unroll
    for (int jj = 0; jj < 6; ++jj) { int j = tid + jj * 256; if (j < KPAD) trow[j] = 0; }
    return;
  }
  const float* xr = x + i * D_DIM;
  float v[6]; float s2 = 0.f;
#pragma unroll
  for (int jj = 0; jj < 6; ++jj) {
    int j = tid + jj * 256;
    v[jj] = (j < D_DIM) ? xr[j] : 0.f;
    s2 += v[jj] * v[jj];
  }
  s2 = block_reduce2<4>(s2, 0.f).x;
  const float nx_t = sqrtf(s2);
  const float nx   = fmaxf(nx_t, EPS);
  const float al   = tanhf(SC * nx) / (SC * nx);
  const float n1   = fmaxf(al * nx_t, EPS);
  const float be   = atanh_f(fminf(SC * n1, 1.f - BEPS)) / (SC * n1);
  const float sca  = al * be;
  if (tid == 0) xn[i] = fmaxf(sca * nx_t, EPS);
#pragma unroll
  for (int jj = 0; jj < 6; ++jj) {
    int j = tid + jj * 256;
    if (j < KPAD) trow[j] = (j < D_DIM) ? f2bf(sca * v[jj]) : (u16)0;
  }
}

__global__ void zero_f(float* p, int n) {
  int i = blockIdx.x * 256 + threadIdx.x;
  if (i < n) p[i] = 0.f;
}

// fold (with inline per-edge Mobius/proj scale):
// pe[e] = (col u16 << 16) | bf16(w_e * S[col]),
//   S[c] from nrm[c] (sum mx^2) and xn[c] (||t||).
__global__ void fold_k(const int* __restrict__ ecol, const float* __restrict__ eval,
                       const float* __restrict__ nrm, const float* __restrict__ xn,
                       u32* __restrict__ pe, int E) {
  const int e = blockIdx.x * 256 + threadIdx.x;
  if (e >= E) return;
  const int c = ecol[e];
  const float realn = sqrtf(nrm[c]);
  const float mxn   = fmaxf(realn, EPS);
  const float xi    = xn[c];
  const float tf    = tanhf((mxn / xi) * atanh_f(fminf(xi, 1.f - BEPS)));
  float S = tf / mxn;
  const float hn = fmaxf(S * realn, EPS);
  const float maxn = 1.f - BEPS;
  if (hn > maxn) S *= maxn / hn;
  pe[e] = ((u32)c << 16) | (u32)f2bf(eval[e] * S);
}

// fused spmm + post (session best form): 256-thread blocks, clamped 12-deep
// edge loop (fully pipelined, no serial remainder). One row per block.
// last==0: writes t_next bf16 (KPAD, zero pad) + xn.  last==1: writes out f32.
__global__ __launch_bounds__(256) void spmm_post(const int* __restrict__ rp,
                                                 const u32* __restrict__ pe,
                                                 const u32* __restrict__ mxp,
                                                 u16* __restrict__ t,
                                                 float* __restrict__ xn,
                                                 float* __restrict__ out,
                                                 const int last) {
  const long r = blockIdx.x;
  const int tid = threadIdx.x;
  if (r >= M_ROWS) {
    if (!last && tid < 184) {            // 184 * 4 u32 = 736 = KPAD/2 words
      u32* trow32 = (u32*)(t + r * KPAD);
#pragma unroll
      for (int k = 0; k < 4; ++k) trow32[4 * tid + k] = 0u;
    }
    return;
  }
  const bool act = tid < 180;           // 180 * 4 u32 = 720 words
  const long boff = 4 * tid;
  float a[8] = {0.f, 0.f, 0.f, 0.f, 0.f, 0.f, 0.f, 0.f};
  const int e0 = rp[r], e1 = rp[r + 1];
  for (int e = e0; e < e1; e += 12) {
    u32 pp[12]; float w[12];
#pragma unroll
    for (int j = 0; j < 12; ++j) {
      const int ee = e + j;
      const int ec = (ee < e1) ? ee : (e1 - 1);
      pp[j] = pe[ec];
      w[j]  = (ee < e1) ? bflo(pp[j]) : 0.f;
    }
    if (act) {
      u32x4 q[12];
#pragma unroll
      for (int j = 0; j < 12; ++j)
        q[j] = *(const u32x4*)&mxp[(long)(pp[j] >> 16) * HP32 + boff];
#pragma unroll
      for (int j = 0; j < 12; ++j) {
#pragma unroll
        for (int k = 0; k < 4; ++k) {
          a[2 * k]     += w[j] * bflo(q[j][k]);
          a[2 * k + 1] += w[j] * bfhi(q[j][k]);
        }
      }
    }
  }
  float s2 = 0.f, s2p = 0.f;
#pragma unroll
  for (int k = 0; k < 8; ++k) {
    const int col = 8 * tid + k;
    const float v = (act && col < D_DIM) ? a[k] : 0.f;
    a[k] = v;
    s2 += v * v;
    const float p = fmaxf(v, 0.f);
    s2p += p * p;
  }
  const float2 red = block_reduce2<4>(s2, s2p);
  const float ns_t  = sqrtf(red.x);
  const float nsp_t = sqrtf(red.y);
  const float maxn = (1.f - BEPS) / SC;
  const float ns = fmaxf(ns_t, EPS);
  const float al = tanhf(SC * ns) / (SC * ns);
  const float n1 = fmaxf(al * ns_t, EPS);
  const float be = (n1 > maxn) ? (maxn / n1) : 1.f;
  const float n2 = fmaxf(be * al * ns_t, EPS);
  const float lam = atanh_f(fminf(SC * n2, 1.f - BEPS)) / (SC * n2);
  const float g = lam * be * al;
  const float na_t = g * nsp_t;
  const float n3 = fmaxf(na_t, EPS);
  const float mu = tanhf(SC * n3) / (SC * n3);
  const float n4 = fmaxf(mu * na_t, EPS);
  const float nu = (n4 > maxn) ? (maxn / n4) : 1.f;
  const float T = nu * mu * g;            // h_out = T * relu(s)
  if (last) {
    if (act) {
      float* orow = out + r * (long)D_DIM;
#pragma unroll
      for (int k = 0; k < 8; ++k) {
        const int col = 8 * tid + k;
        if (col < D_DIM) orow[col] = T * fmaxf(a[k], 0.f);
      }
    }
  } else {
    const float nh_t = T * nsp_t;
    const float n5 = fmaxf(nh_t, EPS);
    const float kap = atanh_f(fminf(SC * n5, 1.f - BEPS)) / (SC * n5);
    const float F = kap * T;              // t_next = F * relu(s)
    if (tid == 0) xn[r] = fmaxf(F * nsp_t, EPS);
    u32* trow32 = (u32*)(t + r * KPAD);
    if (act) {
#pragma unroll
      for (int k = 0; k < 4; ++k)
        trow32[4 * tid + k] = pack2bf(F * fmaxf(a[2 * k], 0.f), F * fmaxf(a[2 * k + 1], 0.f));
    } else if (tid < 184) {
#pragma unroll
      for (int k = 0; k < 4; ++k) trow32[4 * tid + k] = 0u;   // cols [1440,1472)
    }
  }
}

// ---------------- W transpose+cast: Wt[n][k] = bf16(W[k][n]), zero padded ----
// Wt is NPAD rows (n) x KPAD cols (k).
__global__ void wt_conv(const float* __restrict__ W, u16* __restrict__ Wt) {
  __shared__ float tile[32][33];
  const int kb = blockIdx.x * 32, nb = blockIdx.y * 32;
  const int tx = threadIdx.x, ty = threadIdx.y;  // 32x8
#pragma unroll
  for (int r = 0; r < 32; r += 8) {
    const int k = kb + ty + r, n = nb + tx;
    tile[ty + r][tx] = (k < D_DIM && n < D_DIM) ? W[(long)k * D_DIM + n] : 0.f;
  }
  __syncthreads();
#pragma unroll
  for (int r = 0; r < 32; r += 8) {
    const int n = nb + ty + r, k = kb + tx;
    if (n < NPAD && k < KPAD) Wt[(long)n * KPAD + k] = f2bf(tile[tx][ty + r]);
  }
}

// ---------------- CSR build -------------------------------------------------
__global__ void zero_int(int* p, int n) {
  int i = blockIdx.x * 256 + threadIdx.x;
  if (i < n) p[i] = 0;
}
__global__ void hist_k(const int* __restrict__ rows, int* __restrict__ counts, int E) {
  int e = blockIdx.x * 256 + threadIdx.x;
  if (e < E) atomicAdd(&counts[rows[e]], 1);
}
// wave-shuffle scan -- 4 barriers/1024-chunk. Exact integer prefix sum.
__global__ __launch_bounds__(1024) void scan_rp(const int* __restrict__ counts,
                                                int* __restrict__ rp, int n) {
  __shared__ int swv[16];
  __shared__ int carry_s;
  const int tid  = threadIdx.x;
  const int lane = tid & 63;
  const int wid  = tid >> 6;
  if (tid == 0) { carry_s = 0; rp[0] = 0; }
  __syncthreads();
  for (int base = 0; base < n; base += 1024) {
    const int i = base + tid;
    int v = (i < n) ? counts[i] : 0;
#pragma unroll
    for (int off = 1; off < 64; off <<= 1) {
      const int tv = __shfl_up(v, off, 64);
      if (lane >= off) v += tv;
    }
    if (lane == 63) swv[wid] = v;
    __syncthreads();
    if (wid == 0) {
      int s = (lane < 16) ? swv[lane] : 0;
#pragma unroll
      for (int off = 1; off < 16; off <<= 1) {
        const int tv = __shfl_up(s, off, 64);
        if (lane >= off) s += tv;
      }
      if (lane < 16) swv[lane] = s;      // inclusive wave totals
    }
    __syncthreads();
    const int wpfx  = (wid > 0) ? swv[wid - 1] : 0;
    const int carry = carry_s;
    if (i < n) rp[i + 1] = carry + wpfx + v;
    __syncthreads();
    if (tid == 1023) carry_s = carry + swv[15];
    __syncthreads();
  }
}
__global__ void scatter_k(const int* __restrict__ rows, const int* __restrict__ cols,
                          const float* __restrict__ vals, const int* __restrict__ rp,
                          int* __restrict__ cursor, int* __restrict__ ecol,
                          float* __restrict__ eval, int E) {
  int e = blockIdx.x * 256 + threadIdx.x;
  if (e < E) {
    const int r = rows[e];
    const int pos = rp[r] + atomicAdd(&cursor[r], 1);
    ecol[pos] = cols[e];
    eval[pos] = vals[e];
  }
}

// ---------------- launch -----------------------------------------------------
extern "C" void kernel_launch(void* const* d_in, const int* in_sizes, int n_in,
                              void* d_out, int out_size, void* d_ws, size_t ws_size,
                              hipStream_t stream) {
  (void)in_sizes; (void)n_in; (void)out_size; (void)ws_size;
  const float* x    = (const float*)d_in[0];
  const float* W[3] = {(const float*)d_in[1], (const float*)d_in[2], (const float*)d_in[3]};
  const float* vals = (const float*)d_in[4];
  const int*   rows = (const int*)d_in[5];
  const int*   cols = (const int*)d_in[6];
  float* out = (float*)d_out;

  char* base = (char*)d_ws;
  size_t off = 0;
  auto take = [&](size_t bytes) {
    void* q = base + off;
    off = (off + bytes + 255) & ~(size_t)255;
    return q;
  };
  u16*   t    = (u16*)take((size_t)MPAD * KPAD * 2);
  u16*   Wt   = (u16*)take((size_t)NPAD * KPAD * 2);
  u16*   mx   = (u16*)take((size_t)M_ROWS * HPAD * 2);   // bf16 GEMM out
  float* nrm3 = (float*)take((size_t)3 * MPAD * 4);      // per-layer, zeroed once
  float* xn   = (float*)take((size_t)M_ROWS * 4);
  int*   cnt  = (int*)take((size_t)M_ROWS * 2 * 4);      // counts | cursor
  int*   rp   = (int*)take((size_t)(M_ROWS + 1) * 4);
  int*   ecol = (int*)take((size_t)N_EDGE * 4);
  float* eval = (float*)take((size_t)N_EDGE * 4);
  u32*   pe   = (u32*)take((size_t)N_EDGE * 4);

  // CSR build (rows/cols/vals identical across layers)
  zero_int<<<(2 * M_ROWS + 255) / 256, 256, 0, stream>>>(cnt, 2 * M_ROWS);
  hist_k<<<(N_EDGE + 255) / 256, 256, 0, stream>>>(rows, cnt, N_EDGE);
  scan_rp<<<1, 1024, 0, stream>>>(cnt, rp, M_ROWS);
  scatter_k<<<(N_EDGE + 255) / 256, 256, 0, stream>>>(rows, cols, vals, rp,
                                                      cnt + M_ROWS, ecol, eval, N_EDGE);
  zero_f<<<(3 * MPAD + 255) / 256, 256, 0, stream>>>(nrm3, 3 * MPAD);

  pre_k<<<MPAD, 256, 0, stream>>>(x, t, xn);

  for (int L = 0; L < 3; ++L) {
    float* nrm = nrm3 + (size_t)L * MPAD;
    wt_conv<<<dim3(46, 48), dim3(32, 8), 0, stream>>>(W[L], Wt);
    gemm256<<<240, 512, 0, stream>>>(t, Wt, mx, nrm);
    fold_k<<<(N_EDGE + 255) / 256, 256, 0, stream>>>(ecol, eval, nrm, xn, pe, N_EDGE);
    spmm_post<<<MPAD, 256, 0, stream>>>(rp, pe, (const u32*)mx, t, xn, out, (L == 2) ? 1 : 0);
  }
}